// Round 6
// baseline (85.897 us; speedup 1.0000x reference)
//
#include <hip/hip_runtime.h>
#include <hip/hip_fp16.h>
#include <math.h>

// Problem constants (fixed by setup_inputs)
#define BB 16
#define NIN 2048
#define NC 64
#define NF 16
#define BLOCKS_PER_B 64                 /* pass blocks per batch */
#define NPBLK (BB * BLOCKS_PER_B)       /* 1024 pass blocks; also #partials */
// Each pass block: 4 waves x 8 i = 32 i. Per i, lane l / load k in {0,1}
// covers float4-slots s0=2l+128k, s0+1  <->  capsule c=(l>>1)+32k,
// features 8*(l&1) .. 8*(l&1)+7.

__device__ __forceinline__ float dot4(float4 a, float4 b) {
    return a.x * b.x + a.y * b.y + a.z * b.z + a.w * b.w;
}

__device__ __forceinline__ unsigned pack2(float x, float y) {
    __half2 h = __float22half2_rn(make_float2(x, y));
    return *reinterpret_cast<unsigned*>(&h);
}

__device__ __forceinline__ float2 unpack2(unsigned u) {
    __half2 h = *reinterpret_cast<__half2*>(&u);
    return __half22float2(h);
}

__device__ __forceinline__ float4 unpack4(unsigned a, unsigned b) {
    float2 f0 = unpack2(a), f1 = unpack2(b);
    return make_float4(f0.x, f0.y, f1.x, f1.y);
}

// Pass 0: partial sums (fp16) over this block's 32 i, AND emit fp16 input copy.
__global__ __launch_bounds__(256) void pass_mean(const float* __restrict__ in,
                                                 uint2* __restrict__ part2,
                                                 uint4* __restrict__ cp) {
    const int b = blockIdx.x >> 6;
    const int blk = blockIdx.x & 63;
    const int lane = threadIdx.x & 63;
    const int wave = threadIdx.x >> 6;  // 0..3

    const float4* in4 = (const float4*)in;

    float4 acc[4];
#pragma unroll
    for (int k = 0; k < 4; ++k) acc[k] = make_float4(0.f, 0.f, 0.f, 0.f);

#pragma unroll
    for (int t = 0; t < 8; ++t) {
        const size_t i = (size_t)b * NIN + blk * 32 + wave * 8 + t;
        const size_t row = i * 256;  // float4 units
#pragma unroll
        for (int k = 0; k < 2; ++k) {
            float4 v0 = in4[row + 2 * (lane + 64 * k)];
            float4 v1 = in4[row + 2 * (lane + 64 * k) + 1];
            acc[2 * k].x += v0.x; acc[2 * k].y += v0.y;
            acc[2 * k].z += v0.z; acc[2 * k].w += v0.w;
            acc[2 * k + 1].x += v1.x; acc[2 * k + 1].y += v1.y;
            acc[2 * k + 1].z += v1.z; acc[2 * k + 1].w += v1.w;
            uint4 u;
            u.x = pack2(v0.x, v0.y); u.y = pack2(v0.z, v0.w);
            u.z = pack2(v1.x, v1.y); u.w = pack2(v1.z, v1.w);
            cp[i * 128 + lane + 64 * k] = u;
        }
    }

    __shared__ float4 red[4 * 256];
    const int s0a = 2 * lane, s0b = 2 * lane + 128;
    red[wave * 256 + s0a] = acc[0];
    red[wave * 256 + s0a + 1] = acc[1];
    red[wave * 256 + s0b] = acc[2];
    red[wave * 256 + s0b + 1] = acc[3];
    __syncthreads();

    const int t = threadIdx.x;  // slot
    float4 s = red[t];
#pragma unroll
    for (int w = 1; w < 4; ++w) {
        float4 r = red[w * 256 + t];
        s.x += r.x; s.y += r.y; s.z += r.z; s.w += r.w;
    }
    uint2 o;
    o.x = pack2(s.x, s.y);
    o.y = pack2(s.z, s.w);
    part2[blockIdx.x * 256 + t] = o;
}

// Routing pass: read fp16 copy (uint4 = 16B/lane), softmax over caps, weighted
// partial sums (fp16).
__global__ __launch_bounds__(256) void pass_route(const uint4* __restrict__ cp,
                                                  const float* __restrict__ wv,
                                                  uint2* __restrict__ part2) {
    const int b = blockIdx.x >> 6;
    const int blk = blockIdx.x & 63;
    const int lane = threadIdx.x & 63;
    const int wave = threadIdx.x >> 6;  // 0..3
    const float4* wv4 = (const float4*)wv + (size_t)b * 256;

    float4 ow[4];
    ow[0] = wv4[2 * lane];
    ow[1] = wv4[2 * lane + 1];
    ow[2] = wv4[2 * lane + 128];
    ow[3] = wv4[2 * lane + 129];

    float4 acc[4];
#pragma unroll
    for (int k = 0; k < 4; ++k) acc[k] = make_float4(0.f, 0.f, 0.f, 0.f);

#pragma unroll
    for (int t = 0; t < 8; ++t) {
        const size_t i = (size_t)b * NIN + blk * 32 + wave * 8 + t;
        const uint4 u0 = cp[i * 128 + lane];
        const uint4 u1 = cp[i * 128 + lane + 64];
        float4 v00 = unpack4(u0.x, u0.y), v01 = unpack4(u0.z, u0.w);
        float4 v10 = unpack4(u1.x, u1.y), v11 = unpack4(u1.z, u1.w);

        float d0 = dot4(v00, ow[0]) + dot4(v01, ow[1]);
        float d1 = dot4(v10, ow[2]) + dot4(v11, ow[3]);
        d0 += __shfl_xor(d0, 1);  // lane pair completes the 16-feature dot
        d1 += __shfl_xor(d1, 1);

        // softmax over 64 capsules: lane holds caps (lane>>1) and (lane>>1)+32;
        // butterfly over strides {2,4,8,16,32} touches each capsule exactly once
        float m = fmaxf(d0, d1);
        m = fmaxf(m, __shfl_xor(m, 2));
        m = fmaxf(m, __shfl_xor(m, 4));
        m = fmaxf(m, __shfl_xor(m, 8));
        m = fmaxf(m, __shfl_xor(m, 16));
        m = fmaxf(m, __shfl_xor(m, 32));
        float e0 = __expf(d0 - m), e1 = __expf(d1 - m);
        float ss = e0 + e1;
        ss += __shfl_xor(ss, 2);
        ss += __shfl_xor(ss, 4);
        ss += __shfl_xor(ss, 8);
        ss += __shfl_xor(ss, 16);
        ss += __shfl_xor(ss, 32);
        const float inv = 1.0f / ss;
        const float a0 = e0 * inv, a1 = e1 * inv;
        acc[0].x += a0 * v00.x; acc[0].y += a0 * v00.y;
        acc[0].z += a0 * v00.z; acc[0].w += a0 * v00.w;
        acc[1].x += a0 * v01.x; acc[1].y += a0 * v01.y;
        acc[1].z += a0 * v01.z; acc[1].w += a0 * v01.w;
        acc[2].x += a1 * v10.x; acc[2].y += a1 * v10.y;
        acc[2].z += a1 * v10.z; acc[2].w += a1 * v10.w;
        acc[3].x += a1 * v11.x; acc[3].y += a1 * v11.y;
        acc[3].z += a1 * v11.z; acc[3].w += a1 * v11.w;
    }

    __shared__ float4 red[4 * 256];
    const int s0a = 2 * lane, s0b = 2 * lane + 128;
    red[wave * 256 + s0a] = acc[0];
    red[wave * 256 + s0a + 1] = acc[1];
    red[wave * 256 + s0b] = acc[2];
    red[wave * 256 + s0b + 1] = acc[3];
    __syncthreads();

    const int t = threadIdx.x;
    float4 s = red[t];
#pragma unroll
    for (int w = 1; w < 4; ++w) {
        float4 r = red[w * 256 + t];
        s.x += r.x; s.y += r.y; s.z += r.z; s.w += r.w;
    }
    uint2 o;
    o.x = pack2(s.x, s.y);
    o.y = pack2(s.z, s.w);
    part2[blockIdx.x * 256 + t] = o;
}

// Reduce 64 fp16 partials per b, add bias, squash, optionally add prev.
// grid = 1024 blocks: blockIdx = b*64 + c.
__global__ __launch_bounds__(256) void reduce_squash(const uint2* __restrict__ part2,
                                                     const float* __restrict__ bias,
                                                     const float* __restrict__ prev,
                                                     float* __restrict__ dst,
                                                     float scale) {
    const int b = blockIdx.x >> 6;
    const int c = blockIdx.x & 63;
    const int tid = threadIdx.x;
    const int q = tid >> 2;    // partial index 0..63
    const int h4 = tid & 3;    // 4-float group within the 16 features

    const uint2 u = part2[(size_t)(b * BLOCKS_PER_B + q) * 256 + c * 4 + h4];
    const float4 f = unpack4(u.x, u.y);

    __shared__ float lds[1024];
    lds[q * 16 + h4 * 4 + 0] = f.x;
    lds[q * 16 + h4 * 4 + 1] = f.y;
    lds[q * 16 + h4 * 4 + 2] = f.z;
    lds[q * 16 + h4 * 4 + 3] = f.w;
    __syncthreads();

    __shared__ float red[256];
    {
        const int f16 = tid & 15;
        const int qg = tid >> 4;  // 16 groups of 4 q
        float s = 0.f;
#pragma unroll
        for (int j = 0; j < 4; ++j) s += lds[(qg * 4 + j) * 16 + f16];
        red[tid] = s;
    }
    __syncthreads();
    if (tid < 128) red[tid] += red[tid + 128];
    __syncthreads();
    if (tid < 64) red[tid] += red[tid + 64];
    __syncthreads();
    if (tid < 32) red[tid] += red[tid + 32];
    __syncthreads();
    if (tid < 16) {
        float s = (red[tid] + red[tid + 16]) * scale + bias[c * NF + tid];
        float n2 = s * s;
        n2 += __shfl_xor(n2, 1);
        n2 += __shfl_xor(n2, 2);
        n2 += __shfl_xor(n2, 4);
        n2 += __shfl_xor(n2, 8);
        const float sc = n2 / (1.0f + n2) / sqrtf(n2 + 1e-8f);
        float o = s * sc;
        const size_t oi = (size_t)b * 1024 + c * NF + tid;
        if (prev) o += prev[oi];
        dst[oi] = o;
    }
}

extern "C" void kernel_launch(void* const* d_in, const int* in_sizes, int n_in,
                              void* d_out, int out_size, void* d_ws, size_t ws_size,
                              hipStream_t stream) {
    const float* in = (const float*)d_in[0];
    const float* bias = (const float*)d_in[1];
    // num_routing fixed at 3; specialized: priors update is constant along the
    // feature axis => logits_t = dot(in, sum_{s<t} out_s).

    float* ws = (float*)d_ws;
    uint2* part2 = (uint2*)ws;                       // 1024*256 uint2 = 2 MB
    float* out0 = ws + (size_t)NPBLK * 512;          // 16384 floats
    float* osum = out0 + 16384;                      // 16384 floats
    uint4* cp = (uint4*)(osum + 16384);              // fp16 copy, 64 MB

    dim3 grid(NPBLK), blk(256);
    // iter 0: uniform agreements -> mean over i; also emit fp16 copy
    pass_mean<<<grid, blk, 0, stream>>>(in, part2, cp);
    reduce_squash<<<1024, 256, 0, stream>>>(part2, bias, nullptr, out0, 1.0f / 64.0f);
    // iter 1: logits = dot(in, out0)
    pass_route<<<grid, blk, 0, stream>>>(cp, out0, part2);
    reduce_squash<<<1024, 256, 0, stream>>>(part2, bias, out0, osum, 1.0f);
    // iter 2: logits = dot(in, out0 + out1)
    pass_route<<<grid, blk, 0, stream>>>(cp, osum, part2);
    reduce_squash<<<1024, 256, 0, stream>>>(part2, bias, nullptr, (float*)d_out, 1.0f);
}